// Round 1
// baseline (418.102 us; speedup 1.0000x reference)
//
#include <hip/hip_runtime.h>
#include <hip/hip_cooperative_groups.h>
#include <math.h>

namespace cg = cooperative_groups;

#define BATCH 16
#define NPTS 1024
#define DIM 64
#define EPSF 0.1f
#define INV_EPS 10.0f
#define MAX_ITER 100
#define THRESHF 0.1f

__device__ inline float waveSum(float x) {
#pragma unroll
  for (int off = 32; off; off >>= 1) x += __shfl_xor(x, off, 64);
  return x;
}
__device__ inline float waveMax(float x) {
#pragma unroll
  for (int off = 32; off; off >>= 1) x = fmaxf(x, __shfl_xor(x, off, 64));
  return x;
}

// Kernel 1: row softmax over D=64 (one wave per row, lane==d), plus sum(p^2).
// Handles both x (rows [0, B*N)) and y (rows [B*N, 2*B*N)).
__global__ __launch_bounds__(256) void softmax_kernel(
    const float* __restrict__ x, const float* __restrict__ y,
    float* __restrict__ sx, float* __restrict__ sy,
    float* __restrict__ x2, float* __restrict__ y2) {
  int wave = (blockIdx.x * blockDim.x + threadIdx.x) >> 6;
  int lane = threadIdx.x & 63;
  const float* src;
  float* dst;
  float* ss;
  int row;
  if (wave < BATCH * NPTS) {
    src = x; dst = sx; ss = x2; row = wave;
  } else {
    src = y; dst = sy; ss = y2; row = wave - BATCH * NPTS;
  }
  float val = src[(size_t)row * DIM + lane];
  float m = waveMax(val);
  float e = expf(val - m);
  float s = waveSum(e);
  float p = e / s;
  dst[(size_t)row * DIM + lane] = p;
  float sq = waveSum(p * p);
  if (lane == 0) ss[row] = sq;
}

// Kernel 2: K = exp(-C/eps), C = x2_i + y2_j - 2*<sx_i, sy_j>. Writes K and KT.
// 32x32 output tile per block, 256 threads, K-dim = 64 staged in LDS.
#define TILE 32
__global__ __launch_bounds__(256) void buildK_kernel(
    const float* __restrict__ sx, const float* __restrict__ sy,
    const float* __restrict__ x2, const float* __restrict__ y2,
    float* __restrict__ K, float* __restrict__ KT) {
  __shared__ float xs[TILE][DIM + 1];   // +1 pad: kills 32-way bank conflicts
  __shared__ float ys[TILE][DIM + 1];
  __shared__ float tile[TILE][TILE + 1];
  int b = blockIdx.z;
  int i0 = blockIdx.y * TILE;
  int j0 = blockIdx.x * TILE;
  int t = threadIdx.x;

  for (int k = t; k < TILE * DIM; k += 256) {
    int r = k >> 6, c = k & 63;
    xs[r][c] = sx[((size_t)b * NPTS + i0 + r) * DIM + c];
    ys[r][c] = sy[((size_t)b * NPTS + j0 + r) * DIM + c];
  }
  __syncthreads();

  int jj = t & 31;
  int ii0 = t >> 5;  // 0..7
  float acc[4] = {0.f, 0.f, 0.f, 0.f};
#pragma unroll
  for (int d = 0; d < DIM; d++) {
    float yv = ys[jj][d];
#pragma unroll
    for (int r = 0; r < 4; r++) acc[r] = fmaf(xs[ii0 + 8 * r][d], yv, acc[r]);
  }
  float y2v = y2[(size_t)b * NPTS + j0 + jj];
#pragma unroll
  for (int r = 0; r < 4; r++) {
    int ii = ii0 + 8 * r;
    float c = x2[(size_t)b * NPTS + i0 + ii] + y2v - 2.0f * acc[r];
    float kv = expf(-INV_EPS * c);
    K[((size_t)b * NPTS + i0 + ii) * NPTS + j0 + jj] = kv;
    tile[ii][jj] = kv;
  }
  __syncthreads();
  int ii2 = t & 31;
  int jj02 = t >> 5;
#pragma unroll
  for (int r = 0; r < 4; r++) {
    int jj3 = jj02 + 8 * r;
    KT[((size_t)b * NPTS + j0 + jj3) * NPTS + i0 + ii2] = tile[ii2][jj3];
  }
}

// Kernel 3: cooperative Sinkhorn loop + final cost.
// 256 blocks x 512 threads. Block blk owns global rows [blk*64, blk*64+64),
// all inside batch blk>>4. 8 waves/block, 8 rows/wave.
__global__ __launch_bounds__(512) void sinkhorn_kernel(
    const float* __restrict__ K, const float* __restrict__ KT,
    float* __restrict__ u, float* __restrict__ v,
    float* __restrict__ errBuf, float* __restrict__ costAcc,
    float* __restrict__ out) {
  cg::grid_group grid = cg::this_grid();
  __shared__ float sdata[NPTS];  // 4 KB: staged exp(v/eps) or exp(u/eps)
  const int t = threadIdx.x;
  const int blk = blockIdx.x;
  const int wave = t >> 6, lane = t & 63;
  const int batch = blk >> 4;
  const int rowBase = blk * 64;
  const float log_mu = logf((float)(1.0 / 1024.0 + 1e-8));

  // init u=v=0, err buffers, cost accumulator (ws is poisoned each call)
  {
    int gtid = blk * 512 + t;
    if (gtid < BATCH * NPTS) { u[gtid] = 0.f; v[gtid] = 0.f; }
    if (gtid < 2) errBuf[gtid] = 0.f;
    if (gtid == 0) costAcc[0] = 0.f;
  }
  grid.sync();

  int it = 0;
  while (true) {
    // ---- Phase A: u update. stage w_j = exp(v_j/eps) ----
    for (int j = t; j < NPTS; j += 512)
      sdata[j] = expf(INV_EPS * v[batch * NPTS + j]);
    __syncthreads();
    float delta = 0.f;
    for (int rr = 0; rr < 8; rr++) {
      int row = rowBase + wave * 8 + rr;  // global (b,i)
      float uo = u[row];
      const float4* krow = (const float4*)(K + (size_t)row * NPTS);
      const float4* wrow = (const float4*)sdata;
      float4 a = {0.f, 0.f, 0.f, 0.f};
#pragma unroll
      for (int c = 0; c < 4; c++) {
        float4 k4 = krow[lane + 64 * c];
        float4 w4 = wrow[lane + 64 * c];
        a.x = fmaf(k4.x, w4.x, a.x);
        a.y = fmaf(k4.y, w4.y, a.y);
        a.z = fmaf(k4.z, w4.z, a.z);
        a.w = fmaf(k4.w, w4.w, a.w);
      }
      float s = waveSum(a.x + a.y + a.z + a.w);
      s = expf(INV_EPS * uo) * s;  // full Sum_j exp((-C+u+v)/eps)
      float un = EPSF * (log_mu - logf(s + 1e-6f)) + uo;
      delta += fabsf(un - uo);
      if (lane == 0) u[row] = un;
    }
    if (lane == 0) atomicAdd(&errBuf[it & 1], delta);
    grid.sync();

    if (blk == 0 && t == 0) errBuf[(it + 1) & 1] = 0.f;  // safe: all reads done

    // ---- Phase B: v update (uses NEW u). stage a_i = exp(u_i/eps) ----
    for (int i = t; i < NPTS; i += 512)
      sdata[i] = expf(INV_EPS * u[batch * NPTS + i]);
    __syncthreads();
    for (int rr = 0; rr < 8; rr++) {
      int col = rowBase + wave * 8 + rr;  // global (b,j)
      float vo = v[col];
      const float4* krow = (const float4*)(KT + (size_t)col * NPTS);
      const float4* arow = (const float4*)sdata;
      float4 a = {0.f, 0.f, 0.f, 0.f};
#pragma unroll
      for (int c = 0; c < 4; c++) {
        float4 k4 = krow[lane + 64 * c];
        float4 a4 = arow[lane + 64 * c];
        a.x = fmaf(k4.x, a4.x, a.x);
        a.y = fmaf(k4.y, a4.y, a.y);
        a.z = fmaf(k4.z, a4.z, a.z);
        a.w = fmaf(k4.w, a4.w, a.w);
      }
      float s = waveSum(a.x + a.y + a.z + a.w);
      s = expf(INV_EPS * vo) * s;
      float vn = EPSF * (log_mu - logf(s + 1e-6f)) + vo;
      if (lane == 0) v[col] = vn;
    }
    grid.sync();

    float errv = errBuf[it & 1] * (1.0f / (float)BATCH);
    it++;
    if (it >= MAX_ITER || errv < THRESHF) break;
  }

  // ---- Final: cost = mean_b Sum_ij pi*C ; pi = a_i*w_j*K, C = -eps*log(K) ----
  for (int j = t; j < NPTS; j += 512)
    sdata[j] = expf(INV_EPS * v[batch * NPTS + j]);
  __syncthreads();
  float csum = 0.f;
  for (int rr = 0; rr < 8; rr++) {
    int row = rowBase + wave * 8 + rr;
    float ai = expf(INV_EPS * u[row]);
    const float4* krow = (const float4*)(K + (size_t)row * NPTS);
    const float4* wrow = (const float4*)sdata;
#pragma unroll
    for (int c = 0; c < 4; c++) {
      float4 k4 = krow[lane + 64 * c];
      float4 w4 = wrow[lane + 64 * c];
      csum += ai * w4.x * k4.x * (-EPSF * logf(k4.x));
      csum += ai * w4.y * k4.y * (-EPSF * logf(k4.y));
      csum += ai * w4.z * k4.z * (-EPSF * logf(k4.z));
      csum += ai * w4.w * k4.w * (-EPSF * logf(k4.w));
    }
  }
  csum = waveSum(csum);
  if (lane == 0) atomicAdd(costAcc, csum);
  grid.sync();
  if (blk == 0 && t == 0) out[0] = costAcc[0] * (1.0f / (float)BATCH);
}

extern "C" void kernel_launch(void* const* d_in, const int* in_sizes, int n_in,
                              void* d_out, int out_size, void* d_ws,
                              size_t ws_size, hipStream_t stream) {
  (void)in_sizes; (void)n_in; (void)out_size; (void)ws_size;
  const float* x = (const float*)d_in[0];
  const float* y = (const float*)d_in[1];
  float* out = (float*)d_out;

  char* ws = (char*)d_ws;
  size_t off = 0;
  auto alloc = [&](size_t nfloats) -> float* {
    float* p = (float*)(ws + off);
    off += nfloats * sizeof(float);
    return p;
  };
  float* sx = alloc((size_t)BATCH * NPTS * DIM);
  float* sy = alloc((size_t)BATCH * NPTS * DIM);
  float* x2 = alloc((size_t)BATCH * NPTS);
  float* y2 = alloc((size_t)BATCH * NPTS);
  float* u = alloc((size_t)BATCH * NPTS);
  float* v = alloc((size_t)BATCH * NPTS);
  float* errBuf = alloc(2);
  float* costAcc = alloc(2);
  off = (off + 255) & ~(size_t)255;
  float* K = alloc((size_t)BATCH * NPTS * NPTS);
  float* KT = alloc((size_t)BATCH * NPTS * NPTS);

  // softmax: 2*B*N = 32768 waves, 4 waves/block
  softmax_kernel<<<dim3(2 * BATCH * NPTS / 4), 256, 0, stream>>>(x, y, sx, sy,
                                                                 x2, y2);
  // K / KT build: 32x32 tiles
  buildK_kernel<<<dim3(NPTS / TILE, NPTS / TILE, BATCH), 256, 0, stream>>>(
      sx, sy, x2, y2, K, KT);
  // cooperative Sinkhorn loop + cost
  void* args[] = {&K, &KT, &u, &v, &errBuf, &costAcc, &out};
  hipLaunchCooperativeKernel((void*)sinkhorn_kernel, dim3(256), dim3(512),
                             args, 0, stream);
}

// Round 2
// 269.596 us; speedup vs baseline: 1.5508x; 1.5508x over previous
//
#include <hip/hip_runtime.h>
#include <hip/hip_cooperative_groups.h>
#include <math.h>

namespace cg = cooperative_groups;

#define BATCH 16
#define NPTS 1024
#define DIM 64
#define EPSF 0.1f
#define INV_EPS 10.0f
#define MAX_ITER 100
#define THRESHF 0.1f

typedef _Float16 h8 __attribute__((ext_vector_type(8)));

__device__ inline float waveSum(float x) {
#pragma unroll
  for (int off = 32; off; off >>= 1) x += __shfl_xor(x, off, 64);
  return x;
}
__device__ inline float waveMax(float x) {
#pragma unroll
  for (int off = 32; off; off >>= 1) x = fmaxf(x, __shfl_xor(x, off, 64));
  return x;
}

// Kernel 1: row softmax over D=64 (one wave per row, lane==d), plus sum(p^2).
__global__ __launch_bounds__(256) void softmax_kernel(
    const float* __restrict__ x, const float* __restrict__ y,
    float* __restrict__ sx, float* __restrict__ sy,
    float* __restrict__ x2, float* __restrict__ y2) {
  int wave = (blockIdx.x * blockDim.x + threadIdx.x) >> 6;
  int lane = threadIdx.x & 63;
  const float* src;
  float* dst;
  float* ss;
  int row;
  if (wave < BATCH * NPTS) {
    src = x; dst = sx; ss = x2; row = wave;
  } else {
    src = y; dst = sy; ss = y2; row = wave - BATCH * NPTS;
  }
  float val = src[(size_t)row * DIM + lane];
  float m = waveMax(val);
  float e = expf(val - m);
  float s = waveSum(e);
  float p = e / s;
  dst[(size_t)row * DIM + lane] = p;
  float sq = waveSum(p * p);
  if (lane == 0) ss[row] = sq;
}

// Kernel 2: K = exp(-C/eps) stored fp16. 64x64 tile, d-major LDS, 4x4 micro.
#define BT 64
__global__ __launch_bounds__(256) void buildK_kernel(
    const float* __restrict__ sx, const float* __restrict__ sy,
    const float* __restrict__ x2, const float* __restrict__ y2,
    _Float16* __restrict__ K) {
  __shared__ float xs[DIM][BT + 4];
  __shared__ float ys[DIM][BT + 4];
  const int b = blockIdx.z;
  const int i0 = blockIdx.y * BT, j0 = blockIdx.x * BT;
  const int t = threadIdx.x;
  {
    int r = t >> 2, dc = (t & 3) * 16;  // row r, d-chunk of 16
    const float4* xr = (const float4*)(sx + ((size_t)b * NPTS + i0 + r) * DIM + dc);
    const float4* yr = (const float4*)(sy + ((size_t)b * NPTS + j0 + r) * DIM + dc);
#pragma unroll
    for (int c = 0; c < 4; c++) {
      float4 xv = xr[c], yv = yr[c];
      int d = dc + 4 * c;
      xs[d + 0][r] = xv.x; xs[d + 1][r] = xv.y;
      xs[d + 2][r] = xv.z; xs[d + 3][r] = xv.w;
      ys[d + 0][r] = yv.x; ys[d + 1][r] = yv.y;
      ys[d + 2][r] = yv.z; ys[d + 3][r] = yv.w;
    }
  }
  __syncthreads();
  const int tx = t & 15, ty = t >> 4;
  float acc[4][4] = {};
  for (int d = 0; d < DIM; d++) {
    float4 xv = *(const float4*)&xs[d][ty * 4];
    float4 yv = *(const float4*)&ys[d][tx * 4];
    float xa[4] = {xv.x, xv.y, xv.z, xv.w};
    float ya[4] = {yv.x, yv.y, yv.z, yv.w};
#pragma unroll
    for (int a = 0; a < 4; a++)
#pragma unroll
      for (int bb = 0; bb < 4; bb++) acc[a][bb] = fmaf(xa[a], ya[bb], acc[a][bb]);
  }
  const int i = i0 + ty * 4, j = j0 + tx * 4;
  float X2[4], Y2[4];
#pragma unroll
  for (int a = 0; a < 4; a++) X2[a] = x2[(size_t)b * NPTS + i + a];
#pragma unroll
  for (int bb = 0; bb < 4; bb++) Y2[bb] = y2[(size_t)b * NPTS + j + bb];
#pragma unroll
  for (int a = 0; a < 4; a++) {
    union { _Float16 h[4]; short4 s; } pk;
#pragma unroll
    for (int bb = 0; bb < 4; bb++) {
      float C = X2[a] + Y2[bb] - 2.0f * acc[a][bb];
      pk.h[bb] = (_Float16)expf(-INV_EPS * C);
    }
    *(short4*)&K[((size_t)b * NPTS + i + a) * NPTS + j] = pk.s;
  }
}

// Kernel 3: cooperative Sinkhorn, ONE grid sync per iteration.
// 256 blocks x 512 threads; block owns 64 rows of batch blk>>4.
// u lives in registers; v,w live in LDS (redundant per block, identical).
__global__ __launch_bounds__(512) void sinkhorn_kernel(
    const _Float16* __restrict__ K,
    float* __restrict__ partial,   // [2][BATCH][NPTS][16]
    float* __restrict__ errBuf,    // [MAX_ITER+1]
    float* __restrict__ costAcc,
    float* __restrict__ out) {
  cg::grid_group grid = cg::this_grid();
  __shared__ float wLDS[NPTS];
  __shared__ float vLDS[NPTS];
  __shared__ float colpart[8][NPTS];
  __shared__ float derr[8];
  const int t = threadIdx.x;
  const int blk = blockIdx.x;
  const int wave = t >> 6, lane = t & 63;
  const int batch = blk >> 4;
  const int kslot = blk & 15;
  const float log_mu = logf(1.0f / 1024.0f + 1e-8f);

  if (blk == 0) {
    if (t <= MAX_ITER) errBuf[t] = 0.f;
    if (t == 0) costAcc[0] = 0.f;
  }
  for (int j = t; j < NPTS; j += 512) { vLDS[j] = 0.f; wLDS[j] = 1.f; }
  __syncthreads();
  grid.sync();

  float u[8];
#pragma unroll
  for (int r = 0; r < 8; r++) u[r] = 0.f;
  const size_t rowBase = (size_t)batch * NPTS + (size_t)kslot * 64 + wave * 8;

  int it = 0;
  while (true) {
    // ---- Phase A: row pass over K. u update + column partials ----
    const float4* w4 = (const float4*)wLDS;
    float wreg[16];
    *(float4*)&wreg[0]  = w4[2 * lane];
    *(float4*)&wreg[4]  = w4[2 * lane + 1];
    *(float4*)&wreg[8]  = w4[128 + 2 * lane];
    *(float4*)&wreg[12] = w4[128 + 2 * lane + 1];
    float colreg[16];
#pragma unroll
    for (int n = 0; n < 16; n++) colreg[n] = 0.f;
    float delta = 0.f;
#pragma unroll
    for (int rr = 0; rr < 8; rr++) {
      const h8* krow = (const h8*)(K + (rowBase + rr) * NPTS);
      h8 ka = krow[lane], kb = krow[lane + 64];
      float kf[16];
#pragma unroll
      for (int n = 0; n < 8; n++) { kf[n] = (float)ka[n]; kf[8 + n] = (float)kb[n]; }
      float dot = 0.f;
#pragma unroll
      for (int n = 0; n < 16; n++) dot = fmaf(kf[n], wreg[n], dot);
      dot = waveSum(dot);
      float uo = u[rr];
      float s = expf(INV_EPS * uo) * dot;
      float un = EPSF * (log_mu - logf(s + 1e-6f)) + uo;
      delta += fabsf(un - uo);
      u[rr] = un;
      float ai = expf(INV_EPS * un);
#pragma unroll
      for (int n = 0; n < 16; n++) colreg[n] = fmaf(kf[n], ai, colreg[n]);
    }
    if (lane == 0) derr[wave] = delta;
    {  // per-wave column partials -> LDS
      float4* cp = (float4*)&colpart[wave][0];
      cp[2 * lane]       = make_float4(colreg[0], colreg[1], colreg[2], colreg[3]);
      cp[2 * lane + 1]   = make_float4(colreg[4], colreg[5], colreg[6], colreg[7]);
      cp[128 + 2 * lane] = make_float4(colreg[8], colreg[9], colreg[10], colreg[11]);
      cp[128 + 2 * lane + 1] = make_float4(colreg[12], colreg[13], colreg[14], colreg[15]);
    }
    __syncthreads();
    if (t == 0) {
      float e = 0.f;
#pragma unroll
      for (int w = 0; w < 8; w++) e += derr[w];
      atomicAdd(&errBuf[it], e);
    }
    float* pp = partial + ((size_t)(it & 1) * BATCH + batch) * NPTS * 16;
    for (int j = t; j < NPTS; j += 512) {
      float s = 0.f;
#pragma unroll
      for (int w = 0; w < 8; w++) s += colpart[w][j];
      pp[(size_t)j * 16 + kslot] = s;
    }
    grid.sync();

    // ---- Phase B: v update, redundant per block (identical results) ----
    for (int j = t; j < NPTS; j += 512) {
      const float4* pb = (const float4*)(pp + (size_t)j * 16);
      float4 p0 = pb[0], p1 = pb[1], p2 = pb[2], p3 = pb[3];
      float cs = p0.x + p0.y + p0.z + p0.w + p1.x + p1.y + p1.z + p1.w +
                 p2.x + p2.y + p2.z + p2.w + p3.x + p3.y + p3.z + p3.w;
      float vo = vLDS[j];
      float s = expf(INV_EPS * vo) * cs;
      float vn = EPSF * (log_mu - logf(s + 1e-6f)) + vo;
      vLDS[j] = vn;
      wLDS[j] = expf(INV_EPS * vn);
    }
    float errv = errBuf[it] * (1.0f / (float)BATCH);
    it++;
    __syncthreads();
    if (it >= MAX_ITER || errv < THRESHF) break;
  }

  // ---- Final: cost = mean_b sum_ij pi*C ; pi = a_i*K*w_j, C = -eps*log(K) ----
  {
    const float4* w4 = (const float4*)wLDS;
    float wreg[16];
    *(float4*)&wreg[0]  = w4[2 * lane];
    *(float4*)&wreg[4]  = w4[2 * lane + 1];
    *(float4*)&wreg[8]  = w4[128 + 2 * lane];
    *(float4*)&wreg[12] = w4[128 + 2 * lane + 1];
    float csum = 0.f;
#pragma unroll
    for (int rr = 0; rr < 8; rr++) {
      const h8* krow = (const h8*)(K + (rowBase + rr) * NPTS);
      h8 ka = krow[lane], kb = krow[lane + 64];
      float kf[16];
#pragma unroll
      for (int n = 0; n < 8; n++) { kf[n] = (float)ka[n]; kf[8 + n] = (float)kb[n]; }
      float ai = expf(INV_EPS * u[rr]);
#pragma unroll
      for (int n = 0; n < 16; n++) {
        if (kf[n] > 0.f)
          csum += ai * wreg[n] * kf[n] * (-EPSF * logf(kf[n]));
      }
    }
    csum = waveSum(csum);
    if (lane == 0) atomicAdd(costAcc, csum);
  }
  grid.sync();
  if (blk == 0 && t == 0) out[0] = costAcc[0] * (1.0f / (float)BATCH);
}

extern "C" void kernel_launch(void* const* d_in, const int* in_sizes, int n_in,
                              void* d_out, int out_size, void* d_ws,
                              size_t ws_size, hipStream_t stream) {
  (void)in_sizes; (void)n_in; (void)out_size; (void)ws_size;
  const float* x = (const float*)d_in[0];
  const float* y = (const float*)d_in[1];
  float* out = (float*)d_out;

  char* ws = (char*)d_ws;
  size_t off = 0;
  auto allocf = [&](size_t nfloats) -> float* {
    float* p = (float*)(ws + off);
    off += nfloats * sizeof(float);
    return p;
  };
  float* sx = allocf((size_t)BATCH * NPTS * DIM);
  float* sy = allocf((size_t)BATCH * NPTS * DIM);
  float* x2 = allocf((size_t)BATCH * NPTS);
  float* y2 = allocf((size_t)BATCH * NPTS);
  float* partial = allocf((size_t)2 * BATCH * NPTS * 16);
  float* errBuf = allocf(MAX_ITER + 1);
  float* costAcc = allocf(4);
  off = (off + 255) & ~(size_t)255;
  _Float16* K = (_Float16*)(ws + off);
  off += (size_t)BATCH * NPTS * NPTS * sizeof(_Float16);

  softmax_kernel<<<dim3(2 * BATCH * NPTS / 4), 256, 0, stream>>>(x, y, sx, sy,
                                                                 x2, y2);
  buildK_kernel<<<dim3(NPTS / BT, NPTS / BT, BATCH), 256, 0, stream>>>(
      sx, sy, x2, y2, K);
  void* args[] = {&K, &partial, &errBuf, &costAcc, &out};
  hipLaunchCooperativeKernel((void*)sinkhorn_kernel, dim3(256), dim3(512),
                             args, 0, stream);
}

// Round 3
// 212.965 us; speedup vs baseline: 1.9632x; 1.2659x over previous
//
#include <hip/hip_runtime.h>
#include <hip/hip_cooperative_groups.h>
#include <hip/hip_bf16.h>
#include <math.h>

namespace cg = cooperative_groups;

#define BATCH 16
#define NPTS 1024
#define DIM 64
#define EPSF 0.1f
#define INV_EPS 10.0f
#define MAX_ITER 100
#define THRESHF 0.1f

typedef _Float16 h8 __attribute__((ext_vector_type(8)));
typedef short short8v __attribute__((ext_vector_type(8)));
typedef float float4v __attribute__((ext_vector_type(4)));

__device__ inline float waveSum(float x) {
#pragma unroll
  for (int off = 32; off; off >>= 1) x += __shfl_xor(x, off, 64);
  return x;
}
__device__ inline float waveMax(float x) {
#pragma unroll
  for (int off = 32; off; off >>= 1) x = fmaxf(x, __shfl_xor(x, off, 64));
  return x;
}

// Kernel 1: row softmax over D=64 (one wave per row, lane==d).
// Outputs bf16 probabilities (for MFMA) + fp32 sum(p^2).
__global__ __launch_bounds__(256) void softmax_kernel(
    const float* __restrict__ x, const float* __restrict__ y,
    __hip_bfloat16* __restrict__ sxh, __hip_bfloat16* __restrict__ syh,
    float* __restrict__ x2, float* __restrict__ y2) {
  int wave = (blockIdx.x * blockDim.x + threadIdx.x) >> 6;
  int lane = threadIdx.x & 63;
  const float* src;
  __hip_bfloat16* dst;
  float* ss;
  int row;
  if (wave < BATCH * NPTS) {
    src = x; dst = sxh; ss = x2; row = wave;
  } else {
    src = y; dst = syh; ss = y2; row = wave - BATCH * NPTS;
  }
  float val = src[(size_t)row * DIM + lane];
  float m = waveMax(val);
  float e = expf(val - m);
  float s = waveSum(e);
  float p = e / s;
  dst[(size_t)row * DIM + lane] = (__hip_bfloat16)p;
  float sq = waveSum(p * p);
  if (lane == 0) ss[row] = sq;
}

// Kernel 2: K = exp(-C/eps) fp16, C = x2_i + y2_j - 2*<x_i,y_j> via MFMA bf16.
// One 16x16 tile per wave, K=64 as 2 steps of 16x16x32. No LDS.
// A: A[m=lane&15][k=(lane>>4)*8+j]; D: col=lane&15, row=(lane>>4)*4+reg.
__global__ __launch_bounds__(256) void buildK_kernel(
    const __hip_bfloat16* __restrict__ sxh,
    const __hip_bfloat16* __restrict__ syh,
    const float* __restrict__ x2, const float* __restrict__ y2,
    _Float16* __restrict__ K) {
  int wgid = blockIdx.x * 4 + (threadIdx.x >> 6);
  int lane = threadIdx.x & 63;
  int b = wgid >> 12;
  int r = wgid & 4095;
  int i0 = (r >> 6) * 16, j0 = (r & 63) * 16;
  const int m = lane & 15, q = lane >> 4;  // q in 0..3

  const __hip_bfloat16* xrow = sxh + ((size_t)b * NPTS + i0 + m) * DIM + q * 8;
  const __hip_bfloat16* yrow = syh + ((size_t)b * NPTS + j0 + m) * DIM + q * 8;
  short8v a0 = *(const short8v*)xrow;
  short8v b0 = *(const short8v*)yrow;
  short8v a1 = *(const short8v*)(xrow + 32);
  short8v b1 = *(const short8v*)(yrow + 32);
  float4v acc = {0.f, 0.f, 0.f, 0.f};
  acc = __builtin_amdgcn_mfma_f32_16x16x32_bf16(a0, b0, acc, 0, 0, 0);
  acc = __builtin_amdgcn_mfma_f32_16x16x32_bf16(a1, b1, acc, 0, 0, 0);

  float y2v = y2[(size_t)b * NPTS + j0 + m];
  float4 x4 = *(const float4*)(x2 + (size_t)b * NPTS + i0 + q * 4);
  float xa[4] = {x4.x, x4.y, x4.z, x4.w};
#pragma unroll
  for (int reg = 0; reg < 4; reg++) {
    int i = i0 + q * 4 + reg;
    float C = xa[reg] + y2v - 2.0f * acc[reg];
    K[((size_t)b * NPTS + i) * NPTS + j0 + m] = (_Float16)expf(-INV_EPS * C);
  }
}

// Kernel 3: Sinkhorn with per-batch barriers (16 blocks, same XCD) + polled
// cross-batch err exchange. One cooperative grid.sync only for init.
__global__ __launch_bounds__(512) void sinkhorn_kernel(
    const _Float16* __restrict__ K,
    float* __restrict__ partial,   // [2][BATCH][NPTS][16]
    float* __restrict__ deltaPub,  // [2][BATCH][16]
    float* __restrict__ errB,      // [MAX_ITER][BATCH], init -1
    unsigned* __restrict__ batchBar,  // [BATCH*64] padded
    unsigned* __restrict__ doneCnt, float* __restrict__ costAcc,
    float* __restrict__ out) {
  cg::grid_group grid = cg::this_grid();
  __shared__ float wLDS[NPTS];
  __shared__ float vLDS[NPTS];
  __shared__ float colpart[8][NPTS];
  __shared__ float derr[8];
  __shared__ float errbL[BATCH];
  const int t = threadIdx.x;
  const int blk = blockIdx.x;
  const int wave = t >> 6, lane = t & 63;
  // XCD-aware: 16 blocks of a batch share blk%8 -> same XCD (perf heuristic,
  // correctness holds regardless via device-scope atomics).
  const int batch = (blk & 7) + 8 * (blk >> 7);
  const int kslot = (blk >> 3) & 15;
  const float log_mu = logf(1.0f / 1024.0f + 1e-8f);

  for (int j = t; j < NPTS; j += 512) { vLDS[j] = 0.f; wLDS[j] = 1.f; }
  if (blk == 0) {
    for (int i = t; i < MAX_ITER * BATCH; i += 512) errB[i] = -1.0f;
    if (t < BATCH) batchBar[t * 64] = 0u;
    if (t == 0) { doneCnt[0] = 0u; costAcc[0] = 0.f; }
  }
  __syncthreads();
  grid.sync();

  float u[8];
#pragma unroll
  for (int r = 0; r < 8; r++) u[r] = 0.f;
  const size_t rowBase = (size_t)batch * NPTS + (size_t)kslot * 64 + wave * 8;
  unsigned gen = 1;
  int it = 0;

  while (true) {
    // ---- Phase A: u update + column partials ----
    const float4* w4 = (const float4*)wLDS;
    float wreg[16];
    *(float4*)&wreg[0]  = w4[2 * lane];
    *(float4*)&wreg[4]  = w4[2 * lane + 1];
    *(float4*)&wreg[8]  = w4[128 + 2 * lane];
    *(float4*)&wreg[12] = w4[128 + 2 * lane + 1];
    float colreg[16];
#pragma unroll
    for (int n = 0; n < 16; n++) colreg[n] = 0.f;
    float delta = 0.f;
#pragma unroll
    for (int rr = 0; rr < 8; rr++) {
      const h8* krow = (const h8*)(K + (rowBase + rr) * NPTS);
      h8 ka = krow[lane], kb = krow[lane + 64];
      float kf[16];
#pragma unroll
      for (int n = 0; n < 8; n++) { kf[n] = (float)ka[n]; kf[8 + n] = (float)kb[n]; }
      float dot = 0.f;
#pragma unroll
      for (int n = 0; n < 16; n++) dot = fmaf(kf[n], wreg[n], dot);
      dot = waveSum(dot);
      float uo = u[rr];
      float s = expf(INV_EPS * uo) * dot;
      float un = EPSF * (log_mu - logf(s + 1e-6f)) + uo;
      delta += fabsf(un - uo);
      u[rr] = un;
      float ai = expf(INV_EPS * un);
#pragma unroll
      for (int n = 0; n < 16; n++) colreg[n] = fmaf(kf[n], ai, colreg[n]);
    }
    if (lane == 0) derr[wave] = delta;
    {
      float4* cp = (float4*)&colpart[wave][0];
      cp[2 * lane]       = make_float4(colreg[0], colreg[1], colreg[2], colreg[3]);
      cp[2 * lane + 1]   = make_float4(colreg[4], colreg[5], colreg[6], colreg[7]);
      cp[128 + 2 * lane] = make_float4(colreg[8], colreg[9], colreg[10], colreg[11]);
      cp[128 + 2 * lane + 1] = make_float4(colreg[12], colreg[13], colreg[14], colreg[15]);
    }
    __syncthreads();
    float* pp = partial + ((size_t)(it & 1) * BATCH + batch) * NPTS * 16;
    for (int j = t; j < NPTS; j += 512) {
      float s = 0.f;
#pragma unroll
      for (int w = 0; w < 8; w++) s += colpart[w][j];
      pp[(size_t)j * 16 + kslot] = s;
    }
    if (t == 0) {
      float e = 0.f;
#pragma unroll
      for (int w = 0; w < 8; w++) e += derr[w];
      deltaPub[((it & 1) * BATCH + batch) * 16 + kslot] = e;
    }
    __syncthreads();
    // ---- per-batch barrier (16 blocks) ----
    if (t == 0) {
      __hip_atomic_fetch_add(&batchBar[batch * 64], 1u, __ATOMIC_ACQ_REL,
                             __HIP_MEMORY_SCOPE_AGENT);
      while (__hip_atomic_load(&batchBar[batch * 64], __ATOMIC_ACQUIRE,
                               __HIP_MEMORY_SCOPE_AGENT) < 16u * gen)
        __builtin_amdgcn_s_sleep(1);
    }
    __syncthreads();
    gen++;
    // leader publishes deterministic batch err
    if (kslot == 0 && t == 0) {
      const float* dp = deltaPub + ((it & 1) * BATCH + batch) * 16;
      float e = 0.f;
#pragma unroll
      for (int k = 0; k < 16; k++) e += dp[k];
      __hip_atomic_store(&errB[it * BATCH + batch], e, __ATOMIC_RELEASE,
                         __HIP_MEMORY_SCOPE_AGENT);
    }
    // ---- Phase B: v update (redundant per block, identical) ----
    for (int j = t; j < NPTS; j += 512) {
      const float4* pb = (const float4*)(pp + (size_t)j * 16);
      float4 p0 = pb[0], p1 = pb[1], p2 = pb[2], p3 = pb[3];
      float cs = p0.x + p0.y + p0.z + p0.w + p1.x + p1.y + p1.z + p1.w +
                 p2.x + p2.y + p2.z + p2.w + p3.x + p3.y + p3.z + p3.w;
      float vo = vLDS[j];
      float s = expf(INV_EPS * vo) * cs;
      float vn = EPSF * (log_mu - logf(s + 1e-6f)) + vo;
      vLDS[j] = vn;
      wLDS[j] = expf(INV_EPS * vn);
    }
    int itn = it + 1;
    if (itn >= MAX_ITER) { __syncthreads(); break; }
    // ---- cross-batch stop decision: poll all batches' err for this it ----
    if (t < BATCH) {
      float v;
      while ((v = __hip_atomic_load(&errB[it * BATCH + t], __ATOMIC_ACQUIRE,
                                    __HIP_MEMORY_SCOPE_AGENT)) < 0.f)
        __builtin_amdgcn_s_sleep(1);
      errbL[t] = v;
    }
    __syncthreads();
    float errv = 0.f;
#pragma unroll
    for (int k = 0; k < BATCH; k++) errv += errbL[k];
    errv *= (1.0f / (float)BATCH);
    it = itn;
    if (errv < THRESHF) break;
  }

  // ---- Final cost: pi = a_i*K*w_j, C = -eps*log(K) ----
  {
    const float4* w4 = (const float4*)wLDS;
    float wreg[16];
    *(float4*)&wreg[0]  = w4[2 * lane];
    *(float4*)&wreg[4]  = w4[2 * lane + 1];
    *(float4*)&wreg[8]  = w4[128 + 2 * lane];
    *(float4*)&wreg[12] = w4[128 + 2 * lane + 1];
    float csum = 0.f;
#pragma unroll
    for (int rr = 0; rr < 8; rr++) {
      const h8* krow = (const h8*)(K + (rowBase + rr) * NPTS);
      h8 ka = krow[lane], kb = krow[lane + 64];
      float kf[16];
#pragma unroll
      for (int n = 0; n < 8; n++) { kf[n] = (float)ka[n]; kf[8 + n] = (float)kb[n]; }
      float ai = expf(INV_EPS * u[rr]);
#pragma unroll
      for (int n = 0; n < 16; n++) {
        if (kf[n] > 0.f)
          csum += ai * wreg[n] * kf[n] * (-EPSF * logf(kf[n]));
      }
    }
    csum = waveSum(csum);
    if (lane == 0) derr[wave] = csum;
    __syncthreads();
    if (t == 0) {
      float cs = 0.f;
#pragma unroll
      for (int w = 0; w < 8; w++) cs += derr[w];
      atomicAdd(costAcc, cs);
      unsigned old = __hip_atomic_fetch_add(doneCnt, 1u, __ATOMIC_ACQ_REL,
                                            __HIP_MEMORY_SCOPE_AGENT);
      if (old == 255u) {
        float total = __hip_atomic_load(costAcc, __ATOMIC_ACQUIRE,
                                        __HIP_MEMORY_SCOPE_AGENT);
        out[0] = total * (1.0f / (float)BATCH);
      }
    }
  }
}

extern "C" void kernel_launch(void* const* d_in, const int* in_sizes, int n_in,
                              void* d_out, int out_size, void* d_ws,
                              size_t ws_size, hipStream_t stream) {
  (void)in_sizes; (void)n_in; (void)out_size; (void)ws_size;
  const float* x = (const float*)d_in[0];
  const float* y = (const float*)d_in[1];
  float* out = (float*)d_out;

  char* ws = (char*)d_ws;
  size_t off = 0;
  auto alloc = [&](size_t nbytes) -> void* {
    void* p = (void*)(ws + off);
    off = (off + nbytes + 255) & ~(size_t)255;
    return p;
  };
  __hip_bfloat16* sxh = (__hip_bfloat16*)alloc((size_t)BATCH * NPTS * DIM * 2);
  __hip_bfloat16* syh = (__hip_bfloat16*)alloc((size_t)BATCH * NPTS * DIM * 2);
  float* x2 = (float*)alloc((size_t)BATCH * NPTS * 4);
  float* y2 = (float*)alloc((size_t)BATCH * NPTS * 4);
  float* partial = (float*)alloc((size_t)2 * BATCH * NPTS * 16 * 4);
  float* deltaPub = (float*)alloc((size_t)2 * BATCH * 16 * 4);
  float* errB = (float*)alloc((size_t)MAX_ITER * BATCH * 4);
  unsigned* batchBar = (unsigned*)alloc((size_t)BATCH * 64 * 4);
  unsigned* doneCnt = (unsigned*)alloc(64);
  float* costAcc = (float*)alloc(64);
  _Float16* K = (_Float16*)alloc((size_t)BATCH * NPTS * NPTS * 2);

  softmax_kernel<<<dim3(2 * BATCH * NPTS / 4), 256, 0, stream>>>(x, y, sxh, syh,
                                                                 x2, y2);
  buildK_kernel<<<dim3(BATCH * 4096 / 4), 256, 0, stream>>>(sxh, syh, x2, y2, K);
  void* args[] = {&K, &partial, &deltaPub, &errB, &batchBar, &doneCnt,
                  &costAcc, &out};
  hipLaunchCooperativeKernel((void*)sinkhorn_kernel, dim3(256), dim3(512),
                             args, 0, stream);
}

// Round 4
// 185.868 us; speedup vs baseline: 2.2495x; 1.1458x over previous
//
#include <hip/hip_runtime.h>
#include <hip/hip_cooperative_groups.h>
#include <hip/hip_bf16.h>
#include <math.h>

namespace cg = cooperative_groups;

#define BATCH 16
#define NPTS 1024
#define DIM 64
#define EPSF 0.1f
#define INV_EPS 10.0f
#define MAX_ITER 100
#define THRESHF 0.1f

typedef _Float16 h8 __attribute__((ext_vector_type(8)));
typedef short short8v __attribute__((ext_vector_type(8)));
typedef float float4v __attribute__((ext_vector_type(4)));

__device__ inline float waveSum(float x) {
#pragma unroll
  for (int off = 32; off; off >>= 1) x += __shfl_xor(x, off, 64);
  return x;
}
__device__ inline float waveMax(float x) {
#pragma unroll
  for (int off = 32; off; off >>= 1) x = fmaxf(x, __shfl_xor(x, off, 64));
  return x;
}

// Kernel 1: row softmax over D=64 (one wave per row, lane==d).
// Outputs bf16 probabilities (for MFMA) + fp32 sum(p^2).
__global__ __launch_bounds__(256) void softmax_kernel(
    const float* __restrict__ x, const float* __restrict__ y,
    __hip_bfloat16* __restrict__ sxh, __hip_bfloat16* __restrict__ syh,
    float* __restrict__ x2, float* __restrict__ y2) {
  int wave = (blockIdx.x * blockDim.x + threadIdx.x) >> 6;
  int lane = threadIdx.x & 63;
  const float* src;
  __hip_bfloat16* dst;
  float* ss;
  int row;
  if (wave < BATCH * NPTS) {
    src = x; dst = sxh; ss = x2; row = wave;
  } else {
    src = y; dst = syh; ss = y2; row = wave - BATCH * NPTS;
  }
  float val = src[(size_t)row * DIM + lane];
  float m = waveMax(val);
  float e = expf(val - m);
  float s = waveSum(e);
  float p = e / s;
  dst[(size_t)row * DIM + lane] = (__hip_bfloat16)p;
  float sq = waveSum(p * p);
  if (lane == 0) ss[row] = sq;
}

// Kernel 2: K = exp(-C/eps) fp16 via MFMA bf16, 64x64 tile per block.
// LDS-staged fragments (padded stride -> conflict-free b128 reads) and an
// LDS transpose buffer so all global loads/stores are 16 B/lane coalesced.
#define LSTRIDE 72  // shorts; 64 + 8 pad: (9*m+q) mod 8 spreads bank quads
__global__ __launch_bounds__(256) void buildK_kernel(
    const __hip_bfloat16* __restrict__ sxh,
    const __hip_bfloat16* __restrict__ syh,
    const float* __restrict__ x2, const float* __restrict__ y2,
    _Float16* __restrict__ K) {
  __shared__ short xs[64 * LSTRIDE];
  __shared__ short ys[64 * LSTRIDE];
  __shared__ short os[64 * LSTRIDE];
  const int b = blockIdx.z;
  const int i0 = blockIdx.y * 64, j0 = blockIdx.x * 64;
  const int t = threadIdx.x;
  const int wave = t >> 6, lane = t & 63;
  const int m = lane & 15, q = lane >> 4;

  // stage x,y tiles: thread t covers rows t>>3 and 32+(t>>3), 16 B chunk t&7.
  {
    int r = t >> 3, c = t & 7;
    const short8v* xg =
        (const short8v*)(sxh + ((size_t)b * NPTS + i0 + r) * DIM + c * 8);
    const short8v* yg =
        (const short8v*)(syh + ((size_t)b * NPTS + j0 + r) * DIM + c * 8);
    const short8v* xg2 =
        (const short8v*)(sxh + ((size_t)b * NPTS + i0 + 32 + r) * DIM + c * 8);
    const short8v* yg2 =
        (const short8v*)(syh + ((size_t)b * NPTS + j0 + 32 + r) * DIM + c * 8);
    *(short8v*)&xs[r * LSTRIDE + c * 8] = xg[0];
    *(short8v*)&ys[r * LSTRIDE + c * 8] = yg[0];
    *(short8v*)&xs[(32 + r) * LSTRIDE + c * 8] = xg2[0];
    *(short8v*)&ys[(32 + r) * LSTRIDE + c * 8] = yg2[0];
  }
  __syncthreads();

  // wave computes rows [wave*16, wave*16+16) x 64 cols = 4 j-tiles, 8 MFMA.
  short8v a0 = *(const short8v*)&xs[(wave * 16 + m) * LSTRIDE + q * 8];
  short8v a1 = *(const short8v*)&xs[(wave * 16 + m) * LSTRIDE + 32 + q * 8];
  float4v acc[4];
#pragma unroll
  for (int tj = 0; tj < 4; tj++) {
    short8v b0 = *(const short8v*)&ys[(tj * 16 + m) * LSTRIDE + q * 8];
    short8v b1 = *(const short8v*)&ys[(tj * 16 + m) * LSTRIDE + 32 + q * 8];
    float4v c = {0.f, 0.f, 0.f, 0.f};
    c = __builtin_amdgcn_mfma_f32_16x16x32_bf16(a0, b0, c, 0, 0, 0);
    c = __builtin_amdgcn_mfma_f32_16x16x32_bf16(a1, b1, c, 0, 0, 0);
    acc[tj] = c;
  }

  // epilogue: C = x2_i + y2_j - 2*dot; K = exp(-C/eps) -> LDS (fp16)
  float4 x4 = *(const float4*)(x2 + (size_t)b * NPTS + i0 + wave * 16 + q * 4);
  float xa[4] = {x4.x, x4.y, x4.z, x4.w};
#pragma unroll
  for (int tj = 0; tj < 4; tj++) {
    float y2v = y2[(size_t)b * NPTS + j0 + tj * 16 + m];
#pragma unroll
    for (int reg = 0; reg < 4; reg++) {
      float C = xa[reg] + y2v - 2.0f * acc[tj][reg];
      _Float16 kv = (_Float16)expf(-INV_EPS * C);
      os[(wave * 16 + q * 4 + reg) * LSTRIDE + tj * 16 + m] =
          *(const short*)&kv;
    }
  }
  __syncthreads();

  // coalesced store: 16 B/lane, 8 full 128 B row segments per instruction.
  {
    int r = t >> 3, c = t & 7;
    *(short8v*)(K + ((size_t)b * NPTS + i0 + r) * NPTS + j0 + c * 8) =
        *(const short8v*)&os[r * LSTRIDE + c * 8];
    *(short8v*)(K + ((size_t)b * NPTS + i0 + 32 + r) * NPTS + j0 + c * 8) =
        *(const short8v*)&os[(32 + r) * LSTRIDE + c * 8];
  }
}

// Kernel 3: Sinkhorn with per-batch barriers (16 blocks, same XCD) + polled
// cross-batch err exchange. One cooperative grid.sync only for init.
__global__ __launch_bounds__(512) void sinkhorn_kernel(
    const _Float16* __restrict__ K,
    float* __restrict__ partial,   // [2][BATCH][NPTS][16]
    float* __restrict__ deltaPub,  // [2][BATCH][16]
    float* __restrict__ errB,      // [MAX_ITER][BATCH], init -1
    unsigned* __restrict__ batchBar,  // [BATCH*64] padded
    unsigned* __restrict__ doneCnt, float* __restrict__ costAcc,
    float* __restrict__ out) {
  cg::grid_group grid = cg::this_grid();
  __shared__ float wLDS[NPTS];
  __shared__ float vLDS[NPTS];
  __shared__ float colpart[8][NPTS];
  __shared__ float derr[8];
  __shared__ float errbL[BATCH];
  const int t = threadIdx.x;
  const int blk = blockIdx.x;
  const int wave = t >> 6, lane = t & 63;
  // XCD-aware: 16 blocks of a batch share blk%8 -> same XCD (perf heuristic,
  // correctness holds regardless via device-scope atomics).
  const int batch = (blk & 7) + 8 * (blk >> 7);
  const int kslot = (blk >> 3) & 15;
  const float log_mu = logf(1.0f / 1024.0f + 1e-8f);

  for (int j = t; j < NPTS; j += 512) { vLDS[j] = 0.f; wLDS[j] = 1.f; }
  if (blk == 0) {
    for (int i = t; i < MAX_ITER * BATCH; i += 512) errB[i] = -1.0f;
    if (t < BATCH) batchBar[t * 64] = 0u;
    if (t == 0) { doneCnt[0] = 0u; costAcc[0] = 0.f; }
  }
  __syncthreads();
  grid.sync();

  float u[8];
#pragma unroll
  for (int r = 0; r < 8; r++) u[r] = 0.f;
  const size_t rowBase = (size_t)batch * NPTS + (size_t)kslot * 64 + wave * 8;
  unsigned gen = 1;
  int it = 0;

  while (true) {
    // ---- Phase A: u update + column partials ----
    const float4* w4 = (const float4*)wLDS;
    float wreg[16];
    *(float4*)&wreg[0]  = w4[2 * lane];
    *(float4*)&wreg[4]  = w4[2 * lane + 1];
    *(float4*)&wreg[8]  = w4[128 + 2 * lane];
    *(float4*)&wreg[12] = w4[128 + 2 * lane + 1];
    float colreg[16];
#pragma unroll
    for (int n = 0; n < 16; n++) colreg[n] = 0.f;
    float delta = 0.f;
#pragma unroll
    for (int rr = 0; rr < 8; rr++) {
      const h8* krow = (const h8*)(K + (rowBase + rr) * NPTS);
      h8 ka = krow[lane], kb = krow[lane + 64];
      float kf[16];
#pragma unroll
      for (int n = 0; n < 8; n++) { kf[n] = (float)ka[n]; kf[8 + n] = (float)kb[n]; }
      float dot = 0.f;
#pragma unroll
      for (int n = 0; n < 16; n++) dot = fmaf(kf[n], wreg[n], dot);
      dot = waveSum(dot);
      float uo = u[rr];
      float s = expf(INV_EPS * uo) * dot;
      float un = EPSF * (log_mu - logf(s + 1e-6f)) + uo;
      delta += fabsf(un - uo);
      u[rr] = un;
      float ai = expf(INV_EPS * un);
#pragma unroll
      for (int n = 0; n < 16; n++) colreg[n] = fmaf(kf[n], ai, colreg[n]);
    }
    if (lane == 0) derr[wave] = delta;
    {
      float4* cp = (float4*)&colpart[wave][0];
      cp[2 * lane]       = make_float4(colreg[0], colreg[1], colreg[2], colreg[3]);
      cp[2 * lane + 1]   = make_float4(colreg[4], colreg[5], colreg[6], colreg[7]);
      cp[128 + 2 * lane] = make_float4(colreg[8], colreg[9], colreg[10], colreg[11]);
      cp[128 + 2 * lane + 1] = make_float4(colreg[12], colreg[13], colreg[14], colreg[15]);
    }
    __syncthreads();
    float* pp = partial + ((size_t)(it & 1) * BATCH + batch) * NPTS * 16;
    for (int j = t; j < NPTS; j += 512) {
      float s = 0.f;
#pragma unroll
      for (int w = 0; w < 8; w++) s += colpart[w][j];
      pp[(size_t)j * 16 + kslot] = s;
    }
    if (t == 0) {
      float e = 0.f;
#pragma unroll
      for (int w = 0; w < 8; w++) e += derr[w];
      deltaPub[((it & 1) * BATCH + batch) * 16 + kslot] = e;
    }
    __syncthreads();
    // ---- per-batch barrier (16 blocks) ----
    if (t == 0) {
      __hip_atomic_fetch_add(&batchBar[batch * 64], 1u, __ATOMIC_ACQ_REL,
                             __HIP_MEMORY_SCOPE_AGENT);
      while (__hip_atomic_load(&batchBar[batch * 64], __ATOMIC_ACQUIRE,
                               __HIP_MEMORY_SCOPE_AGENT) < 16u * gen)
        __builtin_amdgcn_s_sleep(1);
    }
    __syncthreads();
    gen++;
    // leader publishes deterministic batch err
    if (kslot == 0 && t == 0) {
      const float* dp = deltaPub + ((it & 1) * BATCH + batch) * 16;
      float e = 0.f;
#pragma unroll
      for (int k = 0; k < 16; k++) e += dp[k];
      __hip_atomic_store(&errB[it * BATCH + batch], e, __ATOMIC_RELEASE,
                         __HIP_MEMORY_SCOPE_AGENT);
    }
    // ---- Phase B: v update (redundant per block, identical) ----
    for (int j = t; j < NPTS; j += 512) {
      const float4* pb = (const float4*)(pp + (size_t)j * 16);
      float4 p0 = pb[0], p1 = pb[1], p2 = pb[2], p3 = pb[3];
      float cs = p0.x + p0.y + p0.z + p0.w + p1.x + p1.y + p1.z + p1.w +
                 p2.x + p2.y + p2.z + p2.w + p3.x + p3.y + p3.z + p3.w;
      float vo = vLDS[j];
      float s = expf(INV_EPS * vo) * cs;
      float vn = EPSF * (log_mu - logf(s + 1e-6f)) + vo;
      vLDS[j] = vn;
      wLDS[j] = expf(INV_EPS * vn);
    }
    int itn = it + 1;
    if (itn >= MAX_ITER) { __syncthreads(); break; }
    // ---- cross-batch stop decision: poll all batches' err for this it ----
    if (t < BATCH) {
      float v;
      while ((v = __hip_atomic_load(&errB[it * BATCH + t], __ATOMIC_ACQUIRE,
                                    __HIP_MEMORY_SCOPE_AGENT)) < 0.f)
        __builtin_amdgcn_s_sleep(1);
      errbL[t] = v;
    }
    __syncthreads();
    float errv = 0.f;
#pragma unroll
    for (int k = 0; k < BATCH; k++) errv += errbL[k];
    errv *= (1.0f / (float)BATCH);
    it = itn;
    if (errv < THRESHF) break;
  }

  // ---- Final cost: pi = a_i*K*w_j, C = -eps*log(K) ----
  {
    const float4* w4 = (const float4*)wLDS;
    float wreg[16];
    *(float4*)&wreg[0]  = w4[2 * lane];
    *(float4*)&wreg[4]  = w4[2 * lane + 1];
    *(float4*)&wreg[8]  = w4[128 + 2 * lane];
    *(float4*)&wreg[12] = w4[128 + 2 * lane + 1];
    float csum = 0.f;
#pragma unroll
    for (int rr = 0; rr < 8; rr++) {
      const h8* krow = (const h8*)(K + (rowBase + rr) * NPTS);
      h8 ka = krow[lane], kb = krow[lane + 64];
      float kf[16];
#pragma unroll
      for (int n = 0; n < 8; n++) { kf[n] = (float)ka[n]; kf[8 + n] = (float)kb[n]; }
      float ai = expf(INV_EPS * u[rr]);
#pragma unroll
      for (int n = 0; n < 16; n++) {
        if (kf[n] > 0.f)
          csum += ai * wreg[n] * kf[n] * (-EPSF * logf(kf[n]));
      }
    }
    csum = waveSum(csum);
    if (lane == 0) derr[wave] = csum;
    __syncthreads();
    if (t == 0) {
      float cs = 0.f;
#pragma unroll
      for (int w = 0; w < 8; w++) cs += derr[w];
      atomicAdd(costAcc, cs);
      unsigned old = __hip_atomic_fetch_add(doneCnt, 1u, __ATOMIC_ACQ_REL,
                                            __HIP_MEMORY_SCOPE_AGENT);
      if (old == 255u) {
        float total = __hip_atomic_load(costAcc, __ATOMIC_ACQUIRE,
                                        __HIP_MEMORY_SCOPE_AGENT);
        out[0] = total * (1.0f / (float)BATCH);
      }
    }
  }
}

extern "C" void kernel_launch(void* const* d_in, const int* in_sizes, int n_in,
                              void* d_out, int out_size, void* d_ws,
                              size_t ws_size, hipStream_t stream) {
  (void)in_sizes; (void)n_in; (void)out_size; (void)ws_size;
  const float* x = (const float*)d_in[0];
  const float* y = (const float*)d_in[1];
  float* out = (float*)d_out;

  char* ws = (char*)d_ws;
  size_t off = 0;
  auto alloc = [&](size_t nbytes) -> void* {
    void* p = (void*)(ws + off);
    off = (off + nbytes + 255) & ~(size_t)255;
    return p;
  };
  __hip_bfloat16* sxh = (__hip_bfloat16*)alloc((size_t)BATCH * NPTS * DIM * 2);
  __hip_bfloat16* syh = (__hip_bfloat16*)alloc((size_t)BATCH * NPTS * DIM * 2);
  float* x2 = (float*)alloc((size_t)BATCH * NPTS * 4);
  float* y2 = (float*)alloc((size_t)BATCH * NPTS * 4);
  float* partial = (float*)alloc((size_t)2 * BATCH * NPTS * 16 * 4);
  float* deltaPub = (float*)alloc((size_t)2 * BATCH * 16 * 4);
  float* errB = (float*)alloc((size_t)MAX_ITER * BATCH * 4);
  unsigned* batchBar = (unsigned*)alloc((size_t)BATCH * 64 * 4);
  unsigned* doneCnt = (unsigned*)alloc(64);
  float* costAcc = (float*)alloc(64);
  _Float16* K = (_Float16*)alloc((size_t)BATCH * NPTS * NPTS * 2);

  softmax_kernel<<<dim3(2 * BATCH * NPTS / 4), 256, 0, stream>>>(x, y, sxh, syh,
                                                                 x2, y2);
  buildK_kernel<<<dim3(16, 16, BATCH), 256, 0, stream>>>(sxh, syh, x2, y2, K);
  void* args[] = {&K, &partial, &deltaPub, &errB, &batchBar, &doneCnt,
                  &costAcc, &out};
  hipLaunchCooperativeKernel((void*)sinkhorn_kernel, dim3(256), dim3(512),
                             args, 0, stream);
}